// Round 1
// baseline (563.966 us; speedup 1.0000x reference)
//
#include <hip/hip_runtime.h>

// R-GCN layer: out[v] = sum_{e: dst[e]=v} norm[e] * (h[src[e]] @ W[rel[e]])
//
// v2 strategy (eliminates the 102M-atomicAdd epilogue that dominated v1):
//   T[n, r, :] = (h[n] @ W[r]) as bf16  -- 1.6M rows, plain packed stores
//   edges bucketed by dst (hist/scan/scatter of 8B payload {src*32+rel, norm})
//   k_out: one wave per dst node, lane = out dim; per edge one coalesced
//          128B gather from T + register FMA; single plain store per node.
//   No atomics on out; no out-zero kernel (k_out writes every node).

#define N_NODES 50000
#define N_EDGES 1600000
#define D 64
#define N_REL 32

#define PCHUNK 512
#define PRE_BLOCKS_X 98     // ceil(50000/512)
#define HIST_BLOCKS 782     // ceil(1.6M/2048)

typedef __attribute__((ext_vector_type(8))) __bf16 bf16x8;
typedef __attribute__((ext_vector_type(4))) __bf16 bf16x4;
typedef __attribute__((ext_vector_type(4))) float f32x4;

// ws layout (bytes):
//   [0x000000, 0x040000)  dst_cnt[50000] ints (padded; zeroed region = 200704 B)
//   [0x040000, 0x080000)  offsets[50001] ints
//   [0x080000, 0x100000)  cursor[50000] ints
//   [0x100000, ~0xD35000) payload int2[1.6M]  (12.8 MB)
//   [0xE00000, ...)       T bf16 [N_NODES][rpg][64]  (204.8 MB / G)

__global__ __launch_bounds__(256) void k_zeroc(int* __restrict__ cnt) {
    int i = blockIdx.x * 256 + threadIdx.x;       // 49*256 = 12544 int4 = 200704 B
    ((int4*)cnt)[i] = make_int4(0, 0, 0, 0);
}

__global__ __launch_bounds__(256) void k_hist(const int* __restrict__ dst,
                                              int* __restrict__ cnt) {
    int base = blockIdx.x * 2048 + threadIdx.x;
    #pragma unroll
    for (int rnd = 0; rnd < 8; ++rnd) {
        int e = base + rnd * 256;
        if (e < N_EDGES) atomicAdd(&cnt[dst[e]], 1);
    }
}

// 256 threads; thread t owns nodes [t*196, t*196+196). Serial sums + single-thread
// scan of 256 partials (trivial at this size). Writes offsets AND cursor copies.
__global__ __launch_bounds__(256) void k_scan(const int* __restrict__ cnt,
                                              int* __restrict__ offs,
                                              int* __restrict__ cur) {
    __shared__ int part[257];
    const int t = threadIdx.x;
    const int base = t * 196;
    int s = 0;
    for (int i = 0; i < 196; ++i) {
        int idx = base + i;
        if (idx < N_NODES) s += cnt[idx];
    }
    part[t] = s;
    __syncthreads();
    if (t == 0) {
        int run = 0;
        for (int i = 0; i < 256; ++i) { int v = part[i]; part[i] = run; run += v; }
        part[256] = run;
    }
    __syncthreads();
    int off = part[t];
    for (int i = 0; i < 196; ++i) {
        int idx = base + i;
        if (idx < N_NODES) {
            offs[idx] = off;
            cur[idx] = off;
            off += cnt[idx];
        }
    }
    if (t == 0) offs[N_NODES] = part[256];
}

__global__ __launch_bounds__(256) void k_scatter(
        const int* __restrict__ src, const int* __restrict__ dst,
        const int* __restrict__ rel, const float* __restrict__ norm,
        int* __restrict__ cur, int2* __restrict__ pay) {
    int base = blockIdx.x * 2048 + threadIdx.x;
    #pragma unroll
    for (int rnd = 0; rnd < 8; ++rnd) {
        int e = base + rnd * 256;
        if (e < N_EDGES) {
            int d = dst[e];
            int pos = atomicAdd(&cur[d], 1);
            pay[pos] = make_int2(src[e] * N_REL + rel[e], __float_as_int(norm[e]));
        }
    }
}

// T[n][rl][:] = h[n] @ W[r0+rl], bf16.  Swapped-operand MFMA: mfma(Wfrag, hfrag)
// puts 4 CONSECUTIVE out-dims per C fragment in each lane -> packed 8B stores.
// A-slot (W^T tile): A[m'][k] = W[k][ot*16+m'], element j at k = kt*32+q*8+j.
// B-slot (h^T tile): B[k][n] = h[nodebase+n][k], same k pattern.
// C: lane(q,m): D[row=q*4+reg][col=m] = T[nodebase+m][ot*16+q*4+reg].
__global__ __launch_bounds__(256) void k_pre(
        const float* __restrict__ h, const float* __restrict__ W,
        __bf16* __restrict__ T, int r0, int rpg) {
    const int rl = blockIdx.y;
    const int r = r0 + rl;
    const int chunk0 = blockIdx.x * PCHUNK;
    const int lane = threadIdx.x & 63;
    const int w = threadIdx.x >> 6;
    const int m = lane & 15;
    const int q = lane >> 4;

    const float* Wr = W + (size_t)r * D * D;
    bf16x8 Wf[2][4];
    #pragma unroll
    for (int kt = 0; kt < 2; ++kt) {
        #pragma unroll
        for (int ot = 0; ot < 4; ++ot) {
            bf16x8 b;
            #pragma unroll
            for (int j = 0; j < 8; ++j)
                b[j] = (__bf16)Wr[(kt * 32 + q * 8 + j) * D + ot * 16 + m];
            Wf[kt][ot] = b;
        }
    }

    const int end = min(chunk0 + PCHUNK, N_NODES);
    const f32x4 vzero = {0.f, 0.f, 0.f, 0.f};
    for (int n0 = chunk0; n0 < end; n0 += 64) {
        int node = n0 + w * 16 + m;
        const float* hrow = h + (size_t)min(node, N_NODES - 1) * D;
        f32x4 acc[4];
        #pragma unroll
        for (int ot = 0; ot < 4; ++ot) acc[ot] = vzero;
        #pragma unroll
        for (int kt = 0; kt < 2; ++kt) {
            const float4* ap = (const float4*)(hrow + kt * 32 + q * 8);
            float4 a0 = ap[0];
            float4 a1 = ap[1];
            bf16x8 a;
            a[0] = (__bf16)a0.x; a[1] = (__bf16)a0.y; a[2] = (__bf16)a0.z; a[3] = (__bf16)a0.w;
            a[4] = (__bf16)a1.x; a[5] = (__bf16)a1.y; a[6] = (__bf16)a1.z; a[7] = (__bf16)a1.w;
            #pragma unroll
            for (int ot = 0; ot < 4; ++ot)
                acc[ot] = __builtin_amdgcn_mfma_f32_16x16x32_bf16(Wf[kt][ot], a, acc[ot], 0, 0, 0);
        }
        if (node < N_NODES) {
            __bf16* trow = T + ((size_t)node * rpg + rl) * D;
            #pragma unroll
            for (int ot = 0; ot < 4; ++ot) {
                bf16x4 o;
                o[0] = (__bf16)acc[ot][0];
                o[1] = (__bf16)acc[ot][1];
                o[2] = (__bf16)acc[ot][2];
                o[3] = (__bf16)acc[ot][3];
                *(bf16x4*)(trow + ot * 16 + q * 4) = o;
            }
        }
    }
}

// One wave per dst node; lane = out dim. Per edge: uniform 8B payload load +
// one coalesced 128B line gather from T + FMA. Plain store, no atomics.
__global__ __launch_bounds__(256) void k_out(
        const unsigned short* __restrict__ T, const int* __restrict__ offs,
        const int2* __restrict__ pay, float* __restrict__ out,
        int r0, int r1, int rpg, int first) {
    const int v = (blockIdx.x << 2) + (threadIdx.x >> 6);
    const int lane = threadIdx.x & 63;
    const int s = offs[v];
    const int e = offs[v + 1];
    const size_t orow = ((size_t)v << 6) + lane;

    float acc0 = first ? 0.f : out[orow];
    float acc1 = 0.f;
    int i = s;
    if (rpg == N_REL) {
        // full-table pass: T row index == payload key
        for (; i + 2 <= e; i += 2) {
            int2 p0 = pay[i];
            int2 p1 = pay[i + 1];
            float t0 = __uint_as_float(((unsigned int)T[((size_t)p0.x << 6) + lane]) << 16);
            float t1 = __uint_as_float(((unsigned int)T[((size_t)p1.x << 6) + lane]) << 16);
            acc0 = fmaf(__int_as_float(p0.y), t0, acc0);
            acc1 = fmaf(__int_as_float(p1.y), t1, acc1);
        }
        if (i < e) {
            int2 p = pay[i];
            float t = __uint_as_float(((unsigned int)T[((size_t)p.x << 6) + lane]) << 16);
            acc0 = fmaf(__int_as_float(p.y), t, acc0);
        }
    } else {
        // grouped fallback (small workspace): only rels in [r0, r1)
        for (; i < e; ++i) {
            int2 p = pay[i];
            int rlv = p.x & (N_REL - 1);
            if (rlv >= r0 && rlv < r1) {
                size_t row = (size_t)(p.x >> 5) * rpg + (rlv - r0);
                float t = __uint_as_float(((unsigned int)T[(row << 6) + lane]) << 16);
                acc0 = fmaf(__int_as_float(p.y), t, acc0);
            }
        }
    }
    out[orow] = acc0 + acc1;
}

extern "C" void kernel_launch(void* const* d_in, const int* in_sizes, int n_in,
                              void* d_out, int out_size, void* d_ws, size_t ws_size,
                              hipStream_t stream) {
    const float* h    = (const float*)d_in[0];
    const float* W    = (const float*)d_in[1];
    const int*   src  = (const int*)d_in[2];
    const int*   dst  = (const int*)d_in[3];
    const int*   rel  = (const int*)d_in[4];
    const float* norm = (const float*)d_in[5];
    float* out = (float*)d_out;

    char* ws = (char*)d_ws;
    int*    dst_cnt = (int*)(ws);
    int*    offs    = (int*)(ws + 0x40000);
    int*    cur     = (int*)(ws + 0x80000);
    int2*   pay     = (int2*)(ws + 0x100000);
    __bf16* T       = (__bf16*)(ws + 0xE00000);

    // Pick the largest rel-group size whose T fits the workspace (expect G=1).
    const size_t tbytes_full = (size_t)N_NODES * N_REL * D * sizeof(__bf16); // 204.8 MB
    int G = 1;
    while (G < N_REL) {
        if ((size_t)0xE00000 + tbytes_full / G <= ws_size) break;
        G <<= 1;
    }
    const int rpg = N_REL / G;

    k_zeroc<<<49, 256, 0, stream>>>(dst_cnt);
    k_hist<<<HIST_BLOCKS, 256, 0, stream>>>(dst, dst_cnt);
    k_scan<<<1, 256, 0, stream>>>(dst_cnt, offs, cur);
    k_scatter<<<HIST_BLOCKS, 256, 0, stream>>>(src, dst, rel, norm, cur, pay);

    for (int g = 0; g < G; ++g) {
        k_pre<<<dim3(PRE_BLOCKS_X, rpg), 256, 0, stream>>>(h, W, T, g * rpg, rpg);
        k_out<<<N_NODES / 4, 256, 0, stream>>>((const unsigned short*)T, offs, pay, out,
                                               g * rpg, (g + 1) * rpg, rpg, g == 0);
    }
}

// Round 2
// 410.664 us; speedup vs baseline: 1.3733x; 1.3733x over previous
//
#include <hip/hip_runtime.h>

// R-GCN layer: out[v] = sum_{e: dst[e]=v} norm[e] * (h[src[e]] @ W[rel[e]])
//
// v3: v2 structure (T-table + dst-bucketed edges, atomic-free output) with the
// 140us serial k_scan replaced by a 3-stage parallel scan (~20us), and k_out
// unrolled 4-wide for deeper memory-level parallelism on the random T gathers.

#define N_NODES 50000
#define N_EDGES 1600000
#define D 64
#define N_REL 32

#define PCHUNK 512
#define PRE_BLOCKS_X 98     // ceil(50000/512)
#define HIST_BLOCKS 782     // ceil(1.6M/2048)
#define SCAN_BLOCKS 196     // ceil(50000/256)

typedef __attribute__((ext_vector_type(8))) __bf16 bf16x8;
typedef __attribute__((ext_vector_type(4))) __bf16 bf16x4;
typedef __attribute__((ext_vector_type(4))) float f32x4;

// ws layout (bytes):
//   [0x000000, 0x040000)  dst_cnt[50000] ints (zeroed region = 200704 B)
//   [0x040000, 0x080000)  offsets[50001] ints
//   [0x080000, 0x0F0000)  cursor[50000] ints
//   [0x0F0000, 0x100000)  bsum[196] ints (block sums for scan)
//   [0x100000, 0xD35000)  payload int2[1.6M]  (12.8 MB)
//   [0xE00000, ...)       T bf16 [N_NODES][rpg][64]  (204.8 MB / G)

__global__ __launch_bounds__(256) void k_zeroc(int* __restrict__ cnt) {
    int i = blockIdx.x * 256 + threadIdx.x;       // 49*256 = 12544 int4 = 200704 B
    ((int4*)cnt)[i] = make_int4(0, 0, 0, 0);
}

__global__ __launch_bounds__(256) void k_hist(const int* __restrict__ dst,
                                              int* __restrict__ cnt) {
    int base = blockIdx.x * 2048 + threadIdx.x;
    #pragma unroll
    for (int rnd = 0; rnd < 8; ++rnd) {
        int e = base + rnd * 256;
        if (e < N_EDGES) atomicAdd(&cnt[dst[e]], 1);
    }
}

// Stage 1: per-block sums of 256 counts.
__global__ __launch_bounds__(256) void k_scan1(const int* __restrict__ cnt,
                                               int* __restrict__ bsum) {
    int t = blockIdx.x * 256 + threadIdx.x;
    int c = (t < N_NODES) ? cnt[t] : 0;
    #pragma unroll
    for (int d = 32; d > 0; d >>= 1) c += __shfl_down(c, d, 64);
    __shared__ int ws[4];
    if ((threadIdx.x & 63) == 0) ws[threadIdx.x >> 6] = c;
    __syncthreads();
    if (threadIdx.x == 0) bsum[blockIdx.x] = ws[0] + ws[1] + ws[2] + ws[3];
}

// Stage 2: exclusive scan of the 196 block sums, in place.
__global__ __launch_bounds__(256) void k_scan2(int* __restrict__ bsum) {
    const int t = threadIdx.x;
    const int lane = t & 63;
    const int w = t >> 6;
    int v = (t < SCAN_BLOCKS) ? bsum[t] : 0;
    int x = v;
    #pragma unroll
    for (int d = 1; d < 64; d <<= 1) {
        int n = __shfl_up(x, d, 64);
        if (lane >= d) x += n;
    }
    __shared__ int wt[4];
    if (lane == 63) wt[w] = x;
    __syncthreads();
    if (t == 0) {
        int run = 0;
        #pragma unroll
        for (int i = 0; i < 4; ++i) { int tmp = wt[i]; wt[i] = run; run += tmp; }
    }
    __syncthreads();
    int excl = x - v + wt[w];
    if (t < SCAN_BLOCKS) bsum[t] = excl;
}

// Stage 3: block-level exclusive scan + scanned block offset -> offs, cur.
__global__ __launch_bounds__(256) void k_scan3(const int* __restrict__ cnt,
                                               const int* __restrict__ bsum,
                                               int* __restrict__ offs,
                                               int* __restrict__ cur) {
    const int t = blockIdx.x * 256 + threadIdx.x;
    const int lane = threadIdx.x & 63;
    const int w = threadIdx.x >> 6;
    int c = (t < N_NODES) ? cnt[t] : 0;
    int x = c;
    #pragma unroll
    for (int d = 1; d < 64; d <<= 1) {
        int n = __shfl_up(x, d, 64);
        if (lane >= d) x += n;
    }
    __shared__ int wt[4];
    if (lane == 63) wt[w] = x;
    __syncthreads();
    if (threadIdx.x == 0) {
        int run = 0;
        #pragma unroll
        for (int i = 0; i < 4; ++i) { int tmp = wt[i]; wt[i] = run; run += tmp; }
    }
    __syncthreads();
    int off = x - c + wt[w] + bsum[blockIdx.x];
    if (t < N_NODES) {
        offs[t] = off;
        cur[t] = off;
        if (t == N_NODES - 1) offs[N_NODES] = off + c;
    }
}

__global__ __launch_bounds__(256) void k_scatter(
        const int* __restrict__ src, const int* __restrict__ dst,
        const int* __restrict__ rel, const float* __restrict__ norm,
        int* __restrict__ cur, int2* __restrict__ pay) {
    int base = blockIdx.x * 2048 + threadIdx.x;
    #pragma unroll
    for (int rnd = 0; rnd < 8; ++rnd) {
        int e = base + rnd * 256;
        if (e < N_EDGES) {
            int d = dst[e];
            int pos = atomicAdd(&cur[d], 1);
            pay[pos] = make_int2(src[e] * N_REL + rel[e], __float_as_int(norm[e]));
        }
    }
}

// T[n][rl][:] = h[n] @ W[r0+rl], bf16.  Swapped-operand MFMA: mfma(Wfrag, hfrag)
// puts 4 CONSECUTIVE out-dims per C fragment in each lane -> packed 8B stores.
__global__ __launch_bounds__(256) void k_pre(
        const float* __restrict__ h, const float* __restrict__ W,
        __bf16* __restrict__ T, int r0, int rpg) {
    const int rl = blockIdx.y;
    const int r = r0 + rl;
    const int chunk0 = blockIdx.x * PCHUNK;
    const int lane = threadIdx.x & 63;
    const int w = threadIdx.x >> 6;
    const int m = lane & 15;
    const int q = lane >> 4;

    const float* Wr = W + (size_t)r * D * D;
    bf16x8 Wf[2][4];
    #pragma unroll
    for (int kt = 0; kt < 2; ++kt) {
        #pragma unroll
        for (int ot = 0; ot < 4; ++ot) {
            bf16x8 b;
            #pragma unroll
            for (int j = 0; j < 8; ++j)
                b[j] = (__bf16)Wr[(kt * 32 + q * 8 + j) * D + ot * 16 + m];
            Wf[kt][ot] = b;
        }
    }

    const int end = min(chunk0 + PCHUNK, N_NODES);
    const f32x4 vzero = {0.f, 0.f, 0.f, 0.f};
    for (int n0 = chunk0; n0 < end; n0 += 64) {
        int node = n0 + w * 16 + m;
        const float* hrow = h + (size_t)min(node, N_NODES - 1) * D;
        f32x4 acc[4];
        #pragma unroll
        for (int ot = 0; ot < 4; ++ot) acc[ot] = vzero;
        #pragma unroll
        for (int kt = 0; kt < 2; ++kt) {
            const float4* ap = (const float4*)(hrow + kt * 32 + q * 8);
            float4 a0 = ap[0];
            float4 a1 = ap[1];
            bf16x8 a;
            a[0] = (__bf16)a0.x; a[1] = (__bf16)a0.y; a[2] = (__bf16)a0.z; a[3] = (__bf16)a0.w;
            a[4] = (__bf16)a1.x; a[5] = (__bf16)a1.y; a[6] = (__bf16)a1.z; a[7] = (__bf16)a1.w;
            #pragma unroll
            for (int ot = 0; ot < 4; ++ot)
                acc[ot] = __builtin_amdgcn_mfma_f32_16x16x32_bf16(Wf[kt][ot], a, acc[ot], 0, 0, 0);
        }
        if (node < N_NODES) {
            __bf16* trow = T + ((size_t)node * rpg + rl) * D;
            #pragma unroll
            for (int ot = 0; ot < 4; ++ot) {
                bf16x4 o;
                o[0] = (__bf16)acc[ot][0];
                o[1] = (__bf16)acc[ot][1];
                o[2] = (__bf16)acc[ot][2];
                o[3] = (__bf16)acc[ot][3];
                *(bf16x4*)(trow + ot * 16 + q * 4) = o;
            }
        }
    }
}

// One wave per dst node; lane = out dim. Per edge: uniform 8B payload load +
// one coalesced 128B line gather from T + FMA. Plain store, no atomics.
// 4-wide unroll: 4 independent gathers in flight per wave.
__global__ __launch_bounds__(256) void k_out(
        const unsigned short* __restrict__ T, const int* __restrict__ offs,
        const int2* __restrict__ pay, float* __restrict__ out,
        int r0, int r1, int rpg, int first) {
    const int v = (blockIdx.x << 2) + (threadIdx.x >> 6);
    const int lane = threadIdx.x & 63;
    const int s = offs[v];
    const int e = offs[v + 1];
    const size_t orow = ((size_t)v << 6) + lane;

    float acc0 = first ? 0.f : out[orow];
    float acc1 = 0.f, acc2 = 0.f, acc3 = 0.f;
    int i = s;
    if (rpg == N_REL) {
        for (; i + 4 <= e; i += 4) {
            int2 p0 = pay[i];
            int2 p1 = pay[i + 1];
            int2 p2 = pay[i + 2];
            int2 p3 = pay[i + 3];
            float t0 = __uint_as_float(((unsigned int)T[((size_t)p0.x << 6) + lane]) << 16);
            float t1 = __uint_as_float(((unsigned int)T[((size_t)p1.x << 6) + lane]) << 16);
            float t2 = __uint_as_float(((unsigned int)T[((size_t)p2.x << 6) + lane]) << 16);
            float t3 = __uint_as_float(((unsigned int)T[((size_t)p3.x << 6) + lane]) << 16);
            acc0 = fmaf(__int_as_float(p0.y), t0, acc0);
            acc1 = fmaf(__int_as_float(p1.y), t1, acc1);
            acc2 = fmaf(__int_as_float(p2.y), t2, acc2);
            acc3 = fmaf(__int_as_float(p3.y), t3, acc3);
        }
        for (; i < e; ++i) {
            int2 p = pay[i];
            float t = __uint_as_float(((unsigned int)T[((size_t)p.x << 6) + lane]) << 16);
            acc0 = fmaf(__int_as_float(p.y), t, acc0);
        }
    } else {
        // grouped fallback (small workspace): only rels in [r0, r1)
        for (; i < e; ++i) {
            int2 p = pay[i];
            int rlv = p.x & (N_REL - 1);
            if (rlv >= r0 && rlv < r1) {
                size_t row = (size_t)(p.x >> 5) * rpg + (rlv - r0);
                float t = __uint_as_float(((unsigned int)T[(row << 6) + lane]) << 16);
                acc0 = fmaf(__int_as_float(p.y), t, acc0);
            }
        }
    }
    out[orow] = (acc0 + acc1) + (acc2 + acc3);
}

extern "C" void kernel_launch(void* const* d_in, const int* in_sizes, int n_in,
                              void* d_out, int out_size, void* d_ws, size_t ws_size,
                              hipStream_t stream) {
    const float* h    = (const float*)d_in[0];
    const float* W    = (const float*)d_in[1];
    const int*   src  = (const int*)d_in[2];
    const int*   dst  = (const int*)d_in[3];
    const int*   rel  = (const int*)d_in[4];
    const float* norm = (const float*)d_in[5];
    float* out = (float*)d_out;

    char* ws = (char*)d_ws;
    int*    dst_cnt = (int*)(ws);
    int*    offs    = (int*)(ws + 0x40000);
    int*    cur     = (int*)(ws + 0x80000);
    int*    bsum    = (int*)(ws + 0xF0000);
    int2*   pay     = (int2*)(ws + 0x100000);
    __bf16* T       = (__bf16*)(ws + 0xE00000);

    // Pick the largest rel-group size whose T fits the workspace (expect G=1).
    const size_t tbytes_full = (size_t)N_NODES * N_REL * D * sizeof(__bf16); // 204.8 MB
    int G = 1;
    while (G < N_REL) {
        if ((size_t)0xE00000 + tbytes_full / G <= ws_size) break;
        G <<= 1;
    }
    const int rpg = N_REL / G;

    k_zeroc<<<49, 256, 0, stream>>>(dst_cnt);
    k_hist<<<HIST_BLOCKS, 256, 0, stream>>>(dst, dst_cnt);
    k_scan1<<<SCAN_BLOCKS, 256, 0, stream>>>(dst_cnt, bsum);
    k_scan2<<<1, 256, 0, stream>>>(bsum);
    k_scan3<<<SCAN_BLOCKS, 256, 0, stream>>>(dst_cnt, bsum, offs, cur);
    k_scatter<<<HIST_BLOCKS, 256, 0, stream>>>(src, dst, rel, norm, cur, pay);

    for (int g = 0; g < G; ++g) {
        k_pre<<<dim3(PRE_BLOCKS_X, rpg), 256, 0, stream>>>(h, W, T, g * rpg, rpg);
        k_out<<<N_NODES / 4, 256, 0, stream>>>((const unsigned short*)T, offs, pay, out,
                                               g * rpg, (g + 1) * rpg, rpg, g == 0);
    }
}